// Round 1
// baseline (875.732 us; speedup 1.0000x reference)
//
#include <hip/hip_runtime.h>
#include <hip/hip_bf16.h>
#include <math.h>

// Problem constants (match reference)
#define N_NODES 50000
#define N_EDGES 800000
#define IN_F    128
#define EF_F    64
#define NH      4
#define NF      16
#define HF      64          // NH*NF
#define NEG_SLOPE 0.2f

// ---------------------------------------------------------------------------
// K1: fused node kernel.
//  - all threads: grid-stride histogram of dst -> count[] (for CSR build)
//  - wave-per-node GEMV: even waves compute feat_src = feat@W_fc (+ el, er),
//    odd waves compute out = feat@W_res + bias.
//  W column lives in 128 VGPRs per lane; feat row is staged in a per-wave LDS
//  slot and consumed via uniform ds_read_b128 broadcasts (conflict-free).
// ---------------------------------------------------------------------------
__global__ __launch_bounds__(256) void node_kernel(
    const float* __restrict__ feat,
    const float* __restrict__ W_fc,
    const float* __restrict__ W_res,
    const float* __restrict__ attn_l,
    const float* __restrict__ attn_r,
    const float* __restrict__ bias,
    const int*   __restrict__ dst,
    float* __restrict__ feat_src,
    float* __restrict__ el,
    float* __restrict__ er,
    float* __restrict__ out,
    int*   __restrict__ count)
{
    __shared__ __align__(16) float slot[4][IN_F];

    // ---- edge histogram (grid-stride over edges) ----
    int gtid = blockIdx.x * 256 + threadIdx.x;
    int gthreads = gridDim.x * 256;
    for (int e = gtid; e < N_EDGES; e += gthreads)
        atomicAdd(&count[dst[e]], 1);

    // ---- node GEMV ----
    int lane = threadIdx.x & 63;
    int w    = threadIdx.x >> 6;
    int gw   = blockIdx.x * 4 + w;
    int nwav = gridDim.x * 4;
    int kind = gw & 1;              // 0: W_fc path, 1: W_res path
    int gw2  = gw >> 1;
    int nwav2 = nwav >> 1;

    const float* Wm = kind ? W_res : W_fc;
    float Wc[IN_F];
#pragma unroll
    for (int k = 0; k < IN_F; ++k) Wc[k] = Wm[k * HF + lane];

    float al = attn_l[lane];
    float ar = attn_r[lane];
    float bv = bias[lane];

    for (int n = gw2; n < N_NODES; n += nwav2) {
        slot[w][lane]      = feat[n * IN_F + lane];
        slot[w][lane + 64] = feat[n * IN_F + 64 + lane];
        asm volatile("s_waitcnt lgkmcnt(0)" ::: "memory"); // wave-local LDS publish

        const float4* s4 = reinterpret_cast<const float4*>(slot[w]);
        float f0 = 0.f, f1 = 0.f, f2 = 0.f, f3 = 0.f;
#pragma unroll
        for (int k4 = 0; k4 < IN_F / 4; ++k4) {
            float4 c = s4[k4];                 // uniform broadcast read
            f0 += c.x * Wc[k4 * 4 + 0];
            f1 += c.y * Wc[k4 * 4 + 1];
            f2 += c.z * Wc[k4 * 4 + 2];
            f3 += c.w * Wc[k4 * 4 + 3];
        }
        float fs = (f0 + f1) + (f2 + f3);

        if (kind == 0) {
            feat_src[n * HF + lane] = fs;
            float pl = fs * al, pr = fs * ar;
#pragma unroll
            for (int d = 1; d < 16; d <<= 1) {
                pl += __shfl_xor(pl, d, 64);
                pr += __shfl_xor(pr, d, 64);
            }
            if ((lane & 15) == 0) {
                el[n * NH + (lane >> 4)] = pl;
                er[n * NH + (lane >> 4)] = pr;
            }
        } else {
            out[n * HF + lane] = fs + bv;      // residual + bias
        }
    }
}

// ---------------------------------------------------------------------------
// K2: single-block exclusive scan of count[] -> row_ptr[], cursor[]
// ---------------------------------------------------------------------------
__global__ __launch_bounds__(256) void scan_kernel(
    const int* __restrict__ count,
    int* __restrict__ row_ptr,
    int* __restrict__ cursor)
{
    __shared__ int wsum[4];
    __shared__ int chunk_base;
    int tid = threadIdx.x;
    int lane = tid & 63;
    int w = tid >> 6;
    if (tid == 0) chunk_base = 0;
    __syncthreads();

    for (int base = 0; base < N_NODES; base += 256) {
        int i = base + tid;
        int v = (i < N_NODES) ? count[i] : 0;
        int x = v;
#pragma unroll
        for (int d = 1; d < 64; d <<= 1) {
            int y = __shfl_up(x, d, 64);
            if (lane >= d) x += y;
        }
        if (lane == 63) wsum[w] = x;
        __syncthreads();
        int woff = 0;
        for (int k = 0; k < w; ++k) woff += wsum[k];
        int excl = chunk_base + woff + x - v;
        if (i < N_NODES) { row_ptr[i] = excl; cursor[i] = excl; }
        int total = wsum[0] + wsum[1] + wsum[2] + wsum[3];
        __syncthreads();
        if (tid == 0) chunk_base += total;
        __syncthreads();
    }
    if (threadIdx.x == 0) row_ptr[N_NODES] = N_EDGES;
}

// ---------------------------------------------------------------------------
// K3: CSR fill — bucket edge ids by dst via atomic cursors
// ---------------------------------------------------------------------------
__global__ __launch_bounds__(256) void fill_kernel(
    const int* __restrict__ dst,
    int* __restrict__ cursor,
    int* __restrict__ eids)
{
    int e = blockIdx.x * 256 + threadIdx.x;
    if (e < N_EDGES) {
        int p = atomicAdd(&cursor[dst[e]], 1);
        eids[p] = e;
    }
}

// ---------------------------------------------------------------------------
// K4: dst-centric online-softmax aggregation. One wave per node.
//  lane = (h*16 + f) owns output element (h,f).
//  Per edge: GEMV feat_e (W_edge column in 64 VGPRs, edge row broadcast from
//  per-wave LDS slot), ee head-reduce via shfl_xor, leaky-relu logit, online
//  (m,s) rescale, accumulate p*(feat_src[src]+feat_e). Single pass, no
//  atomics, no feat_e materialization.
// ---------------------------------------------------------------------------
__global__ __launch_bounds__(256) void agg_kernel(
    const float* __restrict__ edge_feat,
    const float* __restrict__ W_edge,
    const float* __restrict__ attn_e,
    const float* __restrict__ feat_src,
    const float* __restrict__ el,
    const float* __restrict__ er,
    const int*   __restrict__ src,
    const int*   __restrict__ row_ptr,
    const int*   __restrict__ eids,
    float* __restrict__ out)
{
    __shared__ __align__(16) float slot[4][2][EF_F];

    int lane = threadIdx.x & 63;
    int w    = threadIdx.x >> 6;
    int h    = lane >> 4;
    int gw   = blockIdx.x * 4 + w;
    int nwav = gridDim.x * 4;

    float Wc[EF_F];
#pragma unroll
    for (int k = 0; k < EF_F; ++k) Wc[k] = W_edge[k * HF + lane];
    float ae = attn_e[lane];

    for (int n = gw; n < N_NODES; n += nwav) {
        int beg = row_ptr[n];
        int end = row_ptr[n + 1];
        float acc = 0.f, m = -1e30f, s = 0.f;
        float er_h = er[n * NH + h];

        // one-ahead prefetch of the 256B edge row + scalars
        int   sv = 0;
        float efv = 0.f, elv = 0.f;
        if (beg < end) {
            int e0 = eids[beg];
            sv  = src[e0];
            efv = edge_feat[e0 * EF_F + lane];
            elv = el[sv * NH + h];
        }

        for (int i = beg; i < end; ++i) {
            int   cur_s  = sv;
            float cur_ef = efv;
            float cur_el = elv;
            int p = i & 1;
            slot[w][p][lane] = cur_ef;

            if (i + 1 < end) {
                int e2 = eids[i + 1];
                sv  = src[e2];
                efv = edge_feat[e2 * EF_F + lane];
                elv = el[sv * NH + h];
            }
            float fsv = feat_src[cur_s * HF + lane];

            asm volatile("s_waitcnt lgkmcnt(0)" ::: "memory"); // publish slot
            const float4* s4 = reinterpret_cast<const float4*>(slot[w][p]);
            float f0 = 0.f, f1 = 0.f, f2 = 0.f, f3 = 0.f;
#pragma unroll
            for (int k4 = 0; k4 < EF_F / 4; ++k4) {
                float4 c = s4[k4];             // uniform broadcast read
                f0 += c.x * Wc[k4 * 4 + 0];
                f1 += c.y * Wc[k4 * 4 + 1];
                f2 += c.z * Wc[k4 * 4 + 2];
                f3 += c.w * Wc[k4 * 4 + 3];
            }
            float fe = (f0 + f1) + (f2 + f3);

            // ee[h] = sum over the 16 lanes of this head group
            float prod = fe * ae;
#pragma unroll
            for (int d = 1; d < 16; d <<= 1) prod += __shfl_xor(prod, d, 64);

            float logit = cur_el + er_h + prod;
            logit = (logit > 0.f) ? logit : NEG_SLOPE * logit;

            float mn = fmaxf(m, logit);
            float sc = __expf(m - mn);         // m=-1e30 first iter -> 0
            float pv = __expf(logit - mn);
            s   = s * sc + pv;
            acc = acc * sc + pv * (fsv + fe);
            m   = mn;
        }

        if (beg < end)
            out[n * HF + lane] += acc / s;     // out already holds res+bias
    }
}

// ---------------------------------------------------------------------------
extern "C" void kernel_launch(void* const* d_in, const int* in_sizes, int n_in,
                              void* d_out, int out_size, void* d_ws, size_t ws_size,
                              hipStream_t stream)
{
    (void)in_sizes; (void)n_in; (void)out_size; (void)ws_size;

    const float* feat      = (const float*)d_in[0];
    const float* edge_feat = (const float*)d_in[1];
    const float* W_fc      = (const float*)d_in[2];
    const float* W_edge    = (const float*)d_in[3];
    const float* attn_l    = (const float*)d_in[4];
    const float* attn_r    = (const float*)d_in[5];
    const float* attn_e    = (const float*)d_in[6];
    const float* bias      = (const float*)d_in[7];
    const float* W_res     = (const float*)d_in[8];
    const int*   src       = (const int*)d_in[9];
    const int*   dst       = (const int*)d_in[10];
    float*       out       = (float*)d_out;

    // workspace layout
    float* feat_src = (float*)d_ws;                       // N*64
    float* el       = feat_src + (size_t)N_NODES * HF;    // N*4
    float* er       = el + (size_t)N_NODES * NH;          // N*4
    int*   count    = (int*)(er + (size_t)N_NODES * NH);  // N
    int*   row_ptr  = count + N_NODES;                    // N+1
    int*   cursor   = row_ptr + N_NODES + 1;              // N
    int*   eids     = cursor + N_NODES;                   // E

    hipMemsetAsync(count, 0, N_NODES * sizeof(int), stream);

    node_kernel<<<512, 256, 0, stream>>>(feat, W_fc, W_res, attn_l, attn_r,
                                         bias, dst, feat_src, el, er, out, count);
    scan_kernel<<<1, 256, 0, stream>>>(count, row_ptr, cursor);
    fill_kernel<<<(N_EDGES + 255) / 256, 256, 0, stream>>>(dst, cursor, eids);
    agg_kernel<<<2048, 256, 0, stream>>>(edge_feat, W_edge, attn_e, feat_src,
                                         el, er, src, row_ptr, eids, out);
}